// Round 17
// baseline (127.450 us; speedup 1.0000x reference)
//
#include <hip/hip_runtime.h>
#include <stdint.h>

typedef unsigned short u16;
typedef __attribute__((ext_vector_type(8))) __bf16 bf16x8;
typedef __attribute__((ext_vector_type(8))) short short8;
typedef __attribute__((ext_vector_type(4))) float f32x4;

#define N_NODES 4096
#define DMODEL  512   // 8 heads * 64
#define QKVLD   1536  // Q|K|V concatenated per node
#define KD      64
#define NH      8
#define NSPLIT  4
#define LOG2E   1.4426950408889634f

static __device__ __forceinline__ u16 f2bf(float f) {
  unsigned u = __builtin_bit_cast(unsigned, f);
  u += 0x7fffu + ((u >> 16) & 1u);
  return (u16)(u >> 16);
}

static __device__ __forceinline__ float bf2f(u16 u) {
  return __builtin_bit_cast(float, ((unsigned)u) << 16);
}

static __device__ __forceinline__ f32x4 mfma16(short8 a, short8 b, f32x4 c) {
  return __builtin_amdgcn_mfma_f32_16x16x32_bf16(
      __builtin_bit_cast(bf16x8, a), __builtin_bit_cast(bf16x8, b), c, 0, 0, 0);
}

static __device__ __forceinline__ void gload16(const u16* g, u16* l) {
  __builtin_amdgcn_global_load_lds((const __attribute__((address_space(1))) void*)g,
                                   (__attribute__((address_space(3))) void*)l, 16, 0, 0);
}

// pack 16 f32 (two float4 pairs) into short8 bf16 via cvt_pk (round-to-nearest-even)
static __device__ __forceinline__ short8 cvt8(float4 a, float4 b) {
  unsigned p0, p1, p2, p3;
  asm("v_cvt_pk_bf16_f32 %0, %1, %2" : "=v"(p0) : "v"(a.x), "v"(a.y));
  asm("v_cvt_pk_bf16_f32 %0, %1, %2" : "=v"(p1) : "v"(a.z), "v"(a.w));
  asm("v_cvt_pk_bf16_f32 %0, %1, %2" : "=v"(p2) : "v"(b.x), "v"(b.y));
  asm("v_cvt_pk_bf16_f32 %0, %1, %2" : "=v"(p3) : "v"(b.z), "v"(b.w));
  uint4 u; u.x = p0; u.y = p1; u.z = p2; u.w = p3;
  return __builtin_bit_cast(short8, u);
}

// ---------------- prep: weight packing (merged) ----------------
__global__ void pack_w(const float* __restrict__ Wq, const float* __restrict__ Wk,
                       const float* __restrict__ Wv, const float* __restrict__ Wo,
                       u16* __restrict__ Wt, u16* __restrict__ Wot) {
  __shared__ float t[64][65];
  int z = blockIdx.z;
  int tid = threadIdx.x, lc = tid & 63;
  if (z < 24) {
    int mat = z >> 3, h = z & 7;
    const float* src = (mat == 0) ? Wq : ((mat == 1) ? Wk : Wv);
    float scale = (mat == 0) ? 0.125f * LOG2E : 1.0f;   // exp2-domain scores
    src += (size_t)h * DMODEL * KD;
    u16* dst = Wt + ((size_t)mat * DMODEL + (size_t)h * KD) * DMODEL;
    int r0 = blockIdx.x * 64;      // j tile
#pragma unroll
    for (int i = 0; i < 16; ++i) {
      int row = i * 4 + (tid >> 6);
      t[row][lc] = src[(size_t)(r0 + row) * KD + lc];
    }
    __syncthreads();
#pragma unroll
    for (int i = 0; i < 16; ++i) {
      int row = i * 4 + (tid >> 6);   // k
      dst[(size_t)row * DMODEL + r0 + lc] = f2bf(t[lc][row] * scale);
    }
  } else {
    int r0 = (z - 24) * 64, c0 = blockIdx.x * 64;
#pragma unroll
    for (int i = 0; i < 16; ++i) {
      int row = i * 4 + (tid >> 6);
      t[row][lc] = Wo[(size_t)(r0 + row) * 512 + c0 + lc];
    }
    __syncthreads();
#pragma unroll
    for (int i = 0; i < 16; ++i) {
      int row = i * 4 + (tid >> 6);
      Wot[(size_t)(c0 + row) * 512 + r0 + lc] = f2bf(t[lc][row]);
    }
  }
}

// ---- merged prep: interleaved roles. bid&3==3 -> adjacency bits (512 blocks);
// else QKV GEMM (1536 blocks, m-fastest). __launch_bounds__(256,4) pins the
// allocator to <=128 VGPR so the GEMM path does NOT spill (R15 pathology: the
// bits grid-stride loop made the allocator target 32 VGPR and spill acc[]).
__global__ __launch_bounds__(256, 4) void prep_kernel(const float* __restrict__ X,
                                                      const u16* __restrict__ Bt,
                                                      u16* __restrict__ C,
                                                      u16* __restrict__ Vt,
                                                      const float* __restrict__ adj,
                                                      unsigned long long* __restrict__ bits) {
  __shared__ __align__(16) u16 lA[64 * 64];
  __shared__ __align__(16) u16 lB[64 * 64];
  const int bid = blockIdx.x;
  const int tid = threadIdx.x;
  if ((bid & 3) == 3) {
    // ---- build_bits path (512 blocks, grid-stride) ----
    int bIdx = bid >> 2;
    int gw = ((bIdx << 8) + tid) >> 6;
    int lane = tid & 63;
    for (int word = gw; word < N_NODES * 64; word += 2048) {
      int q = word >> 6, wc = word & 63;
      int k = wc * 64 + lane;
      float v = adj[(size_t)q * N_NODES + k];
      unsigned long long m = __ballot((v != 0.0f) || (q == k));
      if (lane == 0) bits[word] = m;
    }
    return;
  }
  // ---- gemm_qkv path (1536 blocks, m-fastest) ----
  const int g = 3 * (bid >> 2) + (bid & 3);
  const int m0 = (g & 63) * 64, n0 = (g >> 6) * 64;
  const int w = tid >> 6, lane = tid & 63, lm = lane & 15, lg = lane >> 4;
  const int srow = tid >> 2, sc0 = tid & 3;
  f32x4 acc[4] = {};
  for (int k0 = 0; k0 < 512; k0 += 64) {
    __syncthreads();
    {
      const float4* ga = (const float4*)(X + (size_t)(m0 + srow) * 512 + k0);
      short8 s1 = cvt8(ga[2 * sc0], ga[2 * sc0 + 1]);
      short8 s2 = cvt8(ga[2 * (sc0 + 4)], ga[2 * (sc0 + 4) + 1]);
      short8* la = (short8*)(lA + srow * 64);
      la[sc0 ^ (srow & 7)] = s1;
      la[(sc0 + 4) ^ (srow & 7)] = s2;
      const short8* gb = (const short8*)(Bt + (size_t)(n0 + srow) * 512 + k0);
      short8* lb = (short8*)(lB + srow * 64);
      lb[sc0 ^ (srow & 7)] = gb[sc0];
      lb[(sc0 + 4) ^ (srow & 7)] = gb[sc0 + 4];
    }
    __syncthreads();
    short8 af0, af1;
    {
      int row = w * 16 + lm;
      af0 = ((short8*)(lA + row * 64))[lg ^ (row & 7)];
      af1 = ((short8*)(lA + row * 64))[(4 + lg) ^ (row & 7)];
    }
#pragma unroll
    for (int nt = 0; nt < 4; ++nt) {
      int row = nt * 16 + lm;
      short8 b0 = ((short8*)(lB + row * 64))[lg ^ (row & 7)];
      short8 b1 = ((short8*)(lB + row * 64))[(4 + lg) ^ (row & 7)];
      acc[nt] = mfma16(af0, b0, acc[nt]);
      acc[nt] = mfma16(af1, b1, acc[nt]);
    }
  }
#pragma unroll
  for (int nt = 0; nt < 4; ++nt) {
    int n = n0 + nt * 16 + lm;
    int mb = m0 + w * 16 + lg * 4;
    ushort4 o4;
#pragma unroll
    for (int r = 0; r < 4; ++r) ((u16*)&o4)[r] = f2bf(acc[nt][r]);
#pragma unroll
    for (int r = 0; r < 4; ++r) C[(size_t)(mb + r) * QKVLD + n] = ((u16*)&o4)[r];
    if (n >= 1024)      // fused V transpose
      *(ushort4*)(Vt + (size_t)(n - 1024) * N_NODES + mb) = o4;
  }
}

// -------- final GEMM: out_f32[4096][512] = Oc[4096][512] * Wot[512][512]^T --------
__global__ __launch_bounds__(256) void gemm_out(const u16* __restrict__ A,
                                                const u16* __restrict__ Bt,
                                                float* __restrict__ C) {
  __shared__ __align__(16) u16 lA[64 * 64];
  __shared__ __align__(16) u16 lB[64 * 64];
  const int m0 = blockIdx.x * 64, n0 = blockIdx.y * 64;
  const int tid = threadIdx.x;
  const int w = tid >> 6, lane = tid & 63, lm = lane & 15, lg = lane >> 4;
  const int srow = tid >> 2, sc0 = tid & 3;
  f32x4 acc[4] = {};
  for (int k0 = 0; k0 < 512; k0 += 64) {
    __syncthreads();
    {
      const short8* ga = (const short8*)(A + (size_t)(m0 + srow) * 512 + k0);
      short8* la = (short8*)(lA + srow * 64);
      la[sc0 ^ (srow & 7)] = ga[sc0];
      la[(sc0 + 4) ^ (srow & 7)] = ga[sc0 + 4];
      const short8* gb = (const short8*)(Bt + (size_t)(n0 + srow) * 512 + k0);
      short8* lb = (short8*)(lB + srow * 64);
      lb[sc0 ^ (srow & 7)] = gb[sc0];
      lb[(sc0 + 4) ^ (srow & 7)] = gb[sc0 + 4];
    }
    __syncthreads();
    short8 af0, af1;
    {
      int row = w * 16 + lm;
      af0 = ((short8*)(lA + row * 64))[lg ^ (row & 7)];
      af1 = ((short8*)(lA + row * 64))[(4 + lg) ^ (row & 7)];
    }
#pragma unroll
    for (int nt = 0; nt < 4; ++nt) {
      int row = nt * 16 + lm;
      short8 b0 = ((short8*)(lB + row * 64))[lg ^ (row & 7)];
      short8 b1 = ((short8*)(lB + row * 64))[(4 + lg) ^ (row & 7)];
      acc[nt] = mfma16(af0, b0, acc[nt]);
      acc[nt] = mfma16(af1, b1, acc[nt]);
    }
  }
#pragma unroll
  for (int nt = 0; nt < 4; ++nt) {
    int n = n0 + nt * 16 + lm;
    int mb = m0 + w * 16 + lg * 4;
#pragma unroll
    for (int r = 0; r < 4; ++r)
      C[(size_t)(mb + r) * 512 + n] = acc[nt][r];
  }
}

// ---- fused masked attention: R9 structure (8 waves/block, 4 waves/SIMD) ----
// grid 512 x 512thr: h = bid&7, sp = (bid>>3)&3, qb = bid>>5. Block: 256 q, 16 k-blocks.
// Partial outputs written in bf16 (halves Op round-trip traffic).
__global__ __launch_bounds__(512, 4) void attn_kernel(const u16* __restrict__ QKV,
                                                      const u16* __restrict__ Vt,
                                                      const unsigned long long* __restrict__ bits,
                                                      u16* __restrict__ Op,
                                                      float* __restrict__ lp) {
  __shared__ __align__(16) u16 LDSA[16384 + 8 * 2304];
  const int bid = blockIdx.x;
  const int h = bid & 7, sp = (bid >> 3) & 3, qb = bid >> 5;
  const int tid = threadIdx.x;
  const int w = tid >> 6, lane = tid & 63, lm = lane & 15, lg = lane >> 4;
  const int lg4 = lg * 4;
  const int kb0 = sp * 16;                 // 16 key blocks per split

  const int q0 = qb * 256 + w * 32 + lm;   // stream 0 q row
  const int q1 = q0 + 16;                  // stream 1 q row

  const short8 qf00 = *(const short8*)(QKV + (size_t)q0 * QKVLD + h * 64 + lg * 8);
  const short8 qf01 = *(const short8*)(QKV + (size_t)q0 * QKVLD + h * 64 + 32 + lg * 8);
  const short8 qf10 = *(const short8*)(QKV + (size_t)q1 * QKVLD + h * 64 + lg * 8);
  const short8 qf11 = *(const short8*)(QKV + (size_t)q1 * QKVLD + h * 64 + 32 + lg * 8);

  short8 ones;
#pragma unroll
  for (int j = 0; j < 8; ++j) ones[j] = (short)0x3F80;   // bf16 1.0

  // fragment-read vaddrs (buffer/kt/dt via compile-time immediates)
  const int a0 = lm * 64 + (lg ^ (lm & 7)) * 8;
  const u16* rdA = LDSA + a0;
  const u16* rdB = LDSA + (a0 ^ 32);
  // dual P tiles per wave (streams alternate; in-wave DS ordering)
  u16* pW0 = LDSA + 16384 + w * 2304 + lm * 72 + lg4;
  u16* pW1 = pW0 + 1152;
  const u16* pR0 = LDSA + 16384 + w * 2304 + lm * 72 + lg * 8;
  const u16* pR1 = pR0 + 1152;

  // staging: wave w stages rows w*8..w*8+7 (one 16B chunk/lane per matrix)
  const int srow = lane >> 3, sc = lane & 7;
  const int grow = w * 8 + srow;
  const u16* kP = QKV + (size_t)(kb0 * 64 + grow) * QKVLD + 512 + h * 64 + (sc ^ srow) * 8;
  const u16* vP = Vt + ((size_t)h * 64 + grow) * N_NODES + kb0 * 64 + (sc ^ srow) * 8;

#define STAGE(buf) do {                                   \
    gload16(kP, LDSA + (buf) * 4096 + w * 512);           \
    gload16(vP, LDSA + 8192 + (buf) * 4096 + w * 512);    \
  } while (0)
#define ADV() do { kP += 64 * QKVLD; vP += 64; } while (0)

  f32x4 of0[4] = {}, of1[4] = {};
  f32x4 la0 = {}, la1 = {};
  const unsigned long long* bp0 = bits + (size_t)q0 * 64 + kb0;
  const unsigned long long* bp1 = bits + (size_t)q1 * 64 + kb0;

  STAGE(0);
  unsigned long long wb0 = bp0[0], wb1 = bp1[0];

#define SMPACK(sv, wbv, pW, pR, la, paA, paB)                                  \
  do {                                                                         \
    unsigned wlo = (unsigned)((wbv) >> lg4);                                   \
    unsigned whi = ((unsigned)((wbv) >> 32)) >> lg4;                           \
    _Pragma("unroll")                                                          \
    for (int kt = 0; kt < 4; ++kt) {                                           \
      unsigned word = (kt < 2) ? wlo : whi;                                    \
      float pv[4];                                                             \
      _Pragma("unroll")                                                        \
      for (int r = 0; r < 4; ++r) {                                            \
        float e = __builtin_amdgcn_exp2f(sv[kt][r]);                           \
        int mb;                                                                \
        asm("v_bfe_i32 %0, %1, %2, 1" : "=v"(mb)                               \
            : "v"(word), "n"((kt & 1) * 16 + r));                              \
        pv[r] = __builtin_bit_cast(float,                                      \
                   __builtin_bit_cast(unsigned, e) & (unsigned)mb);            \
      }                                                                        \
      unsigned pk0, pk1;                                                       \
      asm("v_cvt_pk_bf16_f32 %0, %1, %2" : "=v"(pk0) : "v"(pv[0]), "v"(pv[1]));\
      asm("v_cvt_pk_bf16_f32 %0, %1, %2" : "=v"(pk1) : "v"(pv[2]), "v"(pv[3]));\
      uint2 pr; pr.x = pk0; pr.y = pk1;                                        \
      *(uint2*)(pW + kt * 16) = pr;                                            \
    }                                                                          \
    paA = *(const short8*)(pR);                                                \
    paB = *(const short8*)(pR + 32);                                           \
    la = mfma16(ones, paA, la);                                                \
    la = mfma16(ones, paB, la);                                                \
  } while (0)

#define BODY(buf, i)                                                           \
  do {                                                                         \
    asm volatile("s_waitcnt vmcnt(0)" ::: "memory");                           \
    __builtin_amdgcn_s_barrier();                                              \
    if ((i) + 1 < 16) { ADV(); STAGE(buf ^ 1); }                               \
    unsigned long long nb0 = ((i) + 1 < 16) ? bp0[(i) + 1] : 0ull;             \
    unsigned long long nb1 = ((i) + 1 < 16) ? bp1[(i) + 1] : 0ull;             \
    f32x4 s0[4], s1[4];                                                        \
    _Pragma("unroll")                                                          \
    for (int kt = 0; kt < 4; ++kt) {                                           \
      short8 k0 = *(const short8*)(rdA + (buf) * 4096 + kt * 1024);            \
      short8 k1 = *(const short8*)(rdB + (buf) * 4096 + kt * 1024);            \
      f32x4 z0 = {0.f, 0.f, 0.f, 0.f}, z1 = {0.f, 0.f, 0.f, 0.f};              \
      z0 = mfma16(k0, qf00, z0); s0[kt] = mfma16(k1, qf01, z0);                \
      z1 = mfma16(k0, qf10, z1); s1[kt] = mfma16(k1, qf11, z1);                \
    }                                                                          \
    short8 pa00, pa01, pa10, pa11;                                             \
    SMPACK(s0, wb0, pW0, pR0, la0, pa00, pa01);                                \
    SMPACK(s1, wb1, pW1, pR1, la1, pa10, pa11);                                \
    _Pragma("unroll")                                                          \
    for (int dt = 0; dt < 4; ++dt) {                                           \
      short8 v0 = *(const short8*)(rdA + 8192 + (buf) * 4096 + dt * 1024);     \
      short8 v1 = *(const short8*)(rdB + 8192 + (buf) * 4096 + dt * 1024);     \
      of0[dt] = mfma16(v0, pa00, of0[dt]);                                     \
      of0[dt] = mfma16(v1, pa01, of0[dt]);                                     \
      of1[dt] = mfma16(v0, pa10, of1[dt]);                                     \
      of1[dt] = mfma16(v1, pa11, of1[dt]);                                     \
    }                                                                          \
    wb0 = nb0; wb1 = nb1;                                                      \
  } while (0)

#pragma unroll 1
  for (int it = 0; it < 8; ++it) {
    BODY(0, it * 2);
    BODY(1, it * 2 + 1);
  }
#undef BODY
#undef SMPACK
#undef STAGE
#undef ADV

  // partial outputs (unnormalized, bf16) + partial l (f32)
  u16* Ob = Op + (size_t)sp * N_NODES * DMODEL;
#pragma unroll
  for (int dt = 0; dt < 4; ++dt) {
    ushort4 o0, o1;
#pragma unroll
    for (int r = 0; r < 4; ++r) {
      ((u16*)&o0)[r] = f2bf(of0[dt][r]);
      ((u16*)&o1)[r] = f2bf(of1[dt][r]);
    }
    *(ushort4*)(Ob + (size_t)q0 * DMODEL + h * 64 + dt * 16 + lg4) = o0;
    *(ushort4*)(Ob + (size_t)q1 * DMODEL + h * 64 + dt * 16 + lg4) = o1;
  }
  if (lg == 0) {
    lp[((size_t)sp * NH + h) * N_NODES + q0] = la0[0];
    lp[((size_t)sp * NH + h) * N_NODES + q1] = la1[0];
  }
}

// combine: Oc[q][hd] = bf16( sum_sp Op[sp][q][hd] / sum_sp l[sp][h][q] )
__global__ __launch_bounds__(256) void combine_kernel(const u16* __restrict__ Op,
                                                      const float* __restrict__ lp,
                                                      u16* __restrict__ Oc) {
  int i = blockIdx.x * 256 + threadIdx.x;      // 4 elements per thread
  int col = (i * 4) & (DMODEL - 1);
  int q = (i * 4) >> 9;
  int h = col >> 6;
  float acc0 = 0.f, acc1 = 0.f, acc2 = 0.f, acc3 = 0.f;
  float l = 0.f;
#pragma unroll
  for (int sp = 0; sp < NSPLIT; ++sp) {
    ushort4 a = ((const ushort4*)(Op + (size_t)sp * N_NODES * DMODEL))[i];
    acc0 += bf2f(a.x); acc1 += bf2f(a.y); acc2 += bf2f(a.z); acc3 += bf2f(a.w);
    l += lp[((size_t)sp * NH + h) * N_NODES + q];
  }
  float inv = 1.0f / l;
  ushort4 o;
  o.x = f2bf(acc0 * inv);
  o.y = f2bf(acc1 * inv);
  o.z = f2bf(acc2 * inv);
  o.w = f2bf(acc3 * inv);
  ((ushort4*)Oc)[i] = o;
}

// ---------------- launcher ----------------

extern "C" void kernel_launch(void* const* d_in, const int* in_sizes, int n_in,
                              void* d_out, int out_size, void* d_ws, size_t ws_size,
                              hipStream_t stream) {
  const float* X   = (const float*)d_in[0];
  const float* Adj = (const float*)d_in[1];
  const float* Wks = (const float*)d_in[2];
  const float* Wqs = (const float*)d_in[3];
  const float* Wvs = (const float*)d_in[4];
  const float* Wo  = (const float*)d_in[5];

  char* p = (char*)d_ws;
  u16* Wt  = (u16*)p; p += (size_t)3 * DMODEL * DMODEL * 2;
  u16* Wot = (u16*)p; p += (size_t)DMODEL * DMODEL * 2;
  u16* QKV = (u16*)p; p += (size_t)N_NODES * QKVLD * 2;
  u16* Vt  = (u16*)p; p += (size_t)N_NODES * DMODEL * 2;
  u16* Oc  = (u16*)p; p += (size_t)N_NODES * DMODEL * 2;
  unsigned long long* bits = (unsigned long long*)p; p += (size_t)N_NODES * 64 * 8;
  u16* Op = (u16*)p; p += (size_t)NSPLIT * N_NODES * DMODEL * 2;
  float* lp = (float*)p; p += (size_t)NSPLIT * NH * N_NODES * 4;

  pack_w<<<dim3(8, 1, 32), dim3(256), 0, stream>>>(Wqs, Wks, Wvs, Wo, Wt, Wot);

  // merged: QKV projection (3 of 4 blocks) || adjacency->bits (1 of 4 blocks)
  prep_kernel<<<dim3(2048), dim3(256), 0, stream>>>(X, Wt, QKV, Vt, Adj, bits);

  attn_kernel<<<dim3(512), dim3(512), 0, stream>>>(QKV, Vt, bits, Op, lp);
  combine_kernel<<<dim3(N_NODES * DMODEL / 4 / 256), dim3(256), 0, stream>>>(Op, lp, Oc);

  gemm_out<<<dim3(64, 8), dim3(256), 0, stream>>>(Oc, Wot, (float*)d_out);
}

// Round 18
// 106.724 us; speedup vs baseline: 1.1942x; 1.1942x over previous
//
#include <hip/hip_runtime.h>
#include <stdint.h>

typedef unsigned short u16;
typedef __attribute__((ext_vector_type(8))) __bf16 bf16x8;
typedef __attribute__((ext_vector_type(8))) short short8;
typedef __attribute__((ext_vector_type(4))) float f32x4;

#define N_NODES 4096
#define DMODEL  512   // 8 heads * 64
#define QKVLD   1536  // Q|K|V concatenated per node
#define KD      64
#define NH      8
#define NSPLIT  4
#define LOG2E   1.4426950408889634f

static __device__ __forceinline__ u16 f2bf(float f) {
  unsigned u = __builtin_bit_cast(unsigned, f);
  u += 0x7fffu + ((u >> 16) & 1u);
  return (u16)(u >> 16);
}

static __device__ __forceinline__ float bf2f(u16 u) {
  return __builtin_bit_cast(float, ((unsigned)u) << 16);
}

static __device__ __forceinline__ f32x4 mfma16(short8 a, short8 b, f32x4 c) {
  return __builtin_amdgcn_mfma_f32_16x16x32_bf16(
      __builtin_bit_cast(bf16x8, a), __builtin_bit_cast(bf16x8, b), c, 0, 0, 0);
}

static __device__ __forceinline__ void gload16(const u16* g, u16* l) {
  __builtin_amdgcn_global_load_lds((const __attribute__((address_space(1))) void*)g,
                                   (__attribute__((address_space(3))) void*)l, 16, 0, 0);
}

// pack 16 f32 (two float4 pairs) into short8 bf16 via cvt_pk (round-to-nearest-even)
static __device__ __forceinline__ short8 cvt8(float4 a, float4 b) {
  unsigned p0, p1, p2, p3;
  asm("v_cvt_pk_bf16_f32 %0, %1, %2" : "=v"(p0) : "v"(a.x), "v"(a.y));
  asm("v_cvt_pk_bf16_f32 %0, %1, %2" : "=v"(p1) : "v"(a.z), "v"(a.w));
  asm("v_cvt_pk_bf16_f32 %0, %1, %2" : "=v"(p2) : "v"(b.x), "v"(b.y));
  asm("v_cvt_pk_bf16_f32 %0, %1, %2" : "=v"(p3) : "v"(b.z), "v"(b.w));
  uint4 u; u.x = p0; u.y = p1; u.z = p2; u.w = p3;
  return __builtin_bit_cast(short8, u);
}

// ---------------- prep: weight packing (merged) ----------------
__global__ void pack_w(const float* __restrict__ Wq, const float* __restrict__ Wk,
                       const float* __restrict__ Wv, const float* __restrict__ Wo,
                       u16* __restrict__ Wt, u16* __restrict__ Wot) {
  __shared__ float t[64][65];
  int z = blockIdx.z;
  int tid = threadIdx.x, lc = tid & 63;
  if (z < 24) {
    int mat = z >> 3, h = z & 7;
    const float* src = (mat == 0) ? Wq : ((mat == 1) ? Wk : Wv);
    float scale = (mat == 0) ? 0.125f * LOG2E : 1.0f;   // exp2-domain scores
    src += (size_t)h * DMODEL * KD;
    u16* dst = Wt + ((size_t)mat * DMODEL + (size_t)h * KD) * DMODEL;
    int r0 = blockIdx.x * 64;      // j tile
#pragma unroll
    for (int i = 0; i < 16; ++i) {
      int row = i * 4 + (tid >> 6);
      t[row][lc] = src[(size_t)(r0 + row) * KD + lc];
    }
    __syncthreads();
#pragma unroll
    for (int i = 0; i < 16; ++i) {
      int row = i * 4 + (tid >> 6);   // k
      dst[(size_t)row * DMODEL + r0 + lc] = f2bf(t[lc][row] * scale);
    }
  } else {
    int r0 = (z - 24) * 64, c0 = blockIdx.x * 64;
#pragma unroll
    for (int i = 0; i < 16; ++i) {
      int row = i * 4 + (tid >> 6);
      t[row][lc] = Wo[(size_t)(r0 + row) * 512 + c0 + lc];
    }
    __syncthreads();
#pragma unroll
    for (int i = 0; i < 16; ++i) {
      int row = i * 4 + (tid >> 6);
      Wot[(size_t)(c0 + row) * 512 + r0 + lc] = f2bf(t[lc][row]);
    }
  }
}

// adjacency (0/1 float, + self loops) -> bit matrix u64[4096][64]
__global__ void build_bits(const float* __restrict__ adj, unsigned long long* __restrict__ bits) {
  int gw = (blockIdx.x * blockDim.x + threadIdx.x) >> 6;
  int lane = threadIdx.x & 63;
  int nw = (gridDim.x * blockDim.x) >> 6;
  for (int word = gw; word < N_NODES * 64; word += nw) {
    int q = word >> 6, wc = word & 63;
    int k = wc * 64 + lane;
    float v = adj[(size_t)q * N_NODES + k];
    unsigned long long m = __ballot((v != 0.0f) || (q == k));
    if (lane == 0) bits[word] = m;
  }
}

// ------- QKV GEMM: C[4096][1536] = X_f32[4096][512] * Wt[1536][512]^T -------
// A staged straight from f32 (conv fused into staging); V columns also write Vt.
__global__ __launch_bounds__(256) void gemm_qkv(const float* __restrict__ X,
                                                const u16* __restrict__ Bt,
                                                u16* __restrict__ C,
                                                u16* __restrict__ Vt) {
  __shared__ __align__(16) u16 lA[64 * 64];
  __shared__ __align__(16) u16 lB[64 * 64];
  const int m0 = blockIdx.x * 64, n0 = blockIdx.y * 64;
  const int tid = threadIdx.x;
  const int w = tid >> 6, lane = tid & 63, lm = lane & 15, lg = lane >> 4;
  const int srow = tid >> 2, sc0 = tid & 3;
  f32x4 acc[4] = {};
  for (int k0 = 0; k0 < 512; k0 += 64) {
    __syncthreads();
    {
      const float4* ga = (const float4*)(X + (size_t)(m0 + srow) * 512 + k0);
      short8 s1 = cvt8(ga[2 * sc0], ga[2 * sc0 + 1]);
      short8 s2 = cvt8(ga[2 * (sc0 + 4)], ga[2 * (sc0 + 4) + 1]);
      short8* la = (short8*)(lA + srow * 64);
      la[sc0 ^ (srow & 7)] = s1;
      la[(sc0 + 4) ^ (srow & 7)] = s2;
      const short8* gb = (const short8*)(Bt + (size_t)(n0 + srow) * 512 + k0);
      short8* lb = (short8*)(lB + srow * 64);
      lb[sc0 ^ (srow & 7)] = gb[sc0];
      lb[(sc0 + 4) ^ (srow & 7)] = gb[sc0 + 4];
    }
    __syncthreads();
    short8 af0, af1;
    {
      int row = w * 16 + lm;
      af0 = ((short8*)(lA + row * 64))[lg ^ (row & 7)];
      af1 = ((short8*)(lA + row * 64))[(4 + lg) ^ (row & 7)];
    }
#pragma unroll
    for (int nt = 0; nt < 4; ++nt) {
      int row = nt * 16 + lm;
      short8 b0 = ((short8*)(lB + row * 64))[lg ^ (row & 7)];
      short8 b1 = ((short8*)(lB + row * 64))[(4 + lg) ^ (row & 7)];
      acc[nt] = mfma16(af0, b0, acc[nt]);
      acc[nt] = mfma16(af1, b1, acc[nt]);
    }
  }
#pragma unroll
  for (int nt = 0; nt < 4; ++nt) {
    int n = n0 + nt * 16 + lm;
    int mb = m0 + w * 16 + lg * 4;
    ushort4 o4;
#pragma unroll
    for (int r = 0; r < 4; ++r) ((u16*)&o4)[r] = f2bf(acc[nt][r]);
#pragma unroll
    for (int r = 0; r < 4; ++r) C[(size_t)(mb + r) * QKVLD + n] = ((u16*)&o4)[r];
    if (n >= 1024)      // fused V transpose
      *(ushort4*)(Vt + (size_t)(n - 1024) * N_NODES + mb) = o4;
  }
}

// -------- final GEMM: out_f32[4096][512] = Oc[4096][512] * Wot[512][512]^T --------
__global__ __launch_bounds__(256) void gemm_out(const u16* __restrict__ A,
                                                const u16* __restrict__ Bt,
                                                float* __restrict__ C) {
  __shared__ __align__(16) u16 lA[64 * 64];
  __shared__ __align__(16) u16 lB[64 * 64];
  const int m0 = blockIdx.x * 64, n0 = blockIdx.y * 64;
  const int tid = threadIdx.x;
  const int w = tid >> 6, lane = tid & 63, lm = lane & 15, lg = lane >> 4;
  const int srow = tid >> 2, sc0 = tid & 3;
  f32x4 acc[4] = {};
  for (int k0 = 0; k0 < 512; k0 += 64) {
    __syncthreads();
    {
      const short8* ga = (const short8*)(A + (size_t)(m0 + srow) * 512 + k0);
      short8* la = (short8*)(lA + srow * 64);
      la[sc0 ^ (srow & 7)] = ga[sc0];
      la[(sc0 + 4) ^ (srow & 7)] = ga[sc0 + 4];
      const short8* gb = (const short8*)(Bt + (size_t)(n0 + srow) * 512 + k0);
      short8* lb = (short8*)(lB + srow * 64);
      lb[sc0 ^ (srow & 7)] = gb[sc0];
      lb[(sc0 + 4) ^ (srow & 7)] = gb[sc0 + 4];
    }
    __syncthreads();
    short8 af0, af1;
    {
      int row = w * 16 + lm;
      af0 = ((short8*)(lA + row * 64))[lg ^ (row & 7)];
      af1 = ((short8*)(lA + row * 64))[(4 + lg) ^ (row & 7)];
    }
#pragma unroll
    for (int nt = 0; nt < 4; ++nt) {
      int row = nt * 16 + lm;
      short8 b0 = ((short8*)(lB + row * 64))[lg ^ (row & 7)];
      short8 b1 = ((short8*)(lB + row * 64))[(4 + lg) ^ (row & 7)];
      acc[nt] = mfma16(af0, b0, acc[nt]);
      acc[nt] = mfma16(af1, b1, acc[nt]);
    }
  }
#pragma unroll
  for (int nt = 0; nt < 4; ++nt) {
    int n = n0 + nt * 16 + lm;
    int mb = m0 + w * 16 + lg * 4;
#pragma unroll
    for (int r = 0; r < 4; ++r)
      C[(size_t)(mb + r) * 512 + n] = acc[nt][r];
  }
}

// ---- fused masked attention: R9 structure (8 waves/block, 4 waves/SIMD) ----
// grid 512 x 512thr: h = bid&7, sp = (bid>>3)&3, qb = bid>>5. Block: 256 q, 16 k-blocks.
// Partial outputs written in bf16 (halves Op round-trip traffic).
__global__ __launch_bounds__(512, 4) void attn_kernel(const u16* __restrict__ QKV,
                                                      const u16* __restrict__ Vt,
                                                      const unsigned long long* __restrict__ bits,
                                                      u16* __restrict__ Op,
                                                      float* __restrict__ lp) {
  __shared__ __align__(16) u16 LDSA[16384 + 8 * 2304];
  const int bid = blockIdx.x;
  const int h = bid & 7, sp = (bid >> 3) & 3, qb = bid >> 5;
  const int tid = threadIdx.x;
  const int w = tid >> 6, lane = tid & 63, lm = lane & 15, lg = lane >> 4;
  const int lg4 = lg * 4;
  const int kb0 = sp * 16;                 // 16 key blocks per split

  const int q0 = qb * 256 + w * 32 + lm;   // stream 0 q row
  const int q1 = q0 + 16;                  // stream 1 q row

  const short8 qf00 = *(const short8*)(QKV + (size_t)q0 * QKVLD + h * 64 + lg * 8);
  const short8 qf01 = *(const short8*)(QKV + (size_t)q0 * QKVLD + h * 64 + 32 + lg * 8);
  const short8 qf10 = *(const short8*)(QKV + (size_t)q1 * QKVLD + h * 64 + lg * 8);
  const short8 qf11 = *(const short8*)(QKV + (size_t)q1 * QKVLD + h * 64 + 32 + lg * 8);

  short8 ones;
#pragma unroll
  for (int j = 0; j < 8; ++j) ones[j] = (short)0x3F80;   // bf16 1.0

  // fragment-read vaddrs (buffer/kt/dt via compile-time immediates)
  const int a0 = lm * 64 + (lg ^ (lm & 7)) * 8;
  const u16* rdA = LDSA + a0;
  const u16* rdB = LDSA + (a0 ^ 32);
  // dual P tiles per wave (streams alternate; in-wave DS ordering)
  u16* pW0 = LDSA + 16384 + w * 2304 + lm * 72 + lg4;
  u16* pW1 = pW0 + 1152;
  const u16* pR0 = LDSA + 16384 + w * 2304 + lm * 72 + lg * 8;
  const u16* pR1 = pR0 + 1152;

  // staging: wave w stages rows w*8..w*8+7 (one 16B chunk/lane per matrix)
  const int srow = lane >> 3, sc = lane & 7;
  const int grow = w * 8 + srow;
  const u16* kP = QKV + (size_t)(kb0 * 64 + grow) * QKVLD + 512 + h * 64 + (sc ^ srow) * 8;
  const u16* vP = Vt + ((size_t)h * 64 + grow) * N_NODES + kb0 * 64 + (sc ^ srow) * 8;

#define STAGE(buf) do {                                   \
    gload16(kP, LDSA + (buf) * 4096 + w * 512);           \
    gload16(vP, LDSA + 8192 + (buf) * 4096 + w * 512);    \
  } while (0)
#define ADV() do { kP += 64 * QKVLD; vP += 64; } while (0)

  f32x4 of0[4] = {}, of1[4] = {};
  f32x4 la0 = {}, la1 = {};
  const unsigned long long* bp0 = bits + (size_t)q0 * 64 + kb0;
  const unsigned long long* bp1 = bits + (size_t)q1 * 64 + kb0;

  STAGE(0);
  unsigned long long wb0 = bp0[0], wb1 = bp1[0];

#define SMPACK(sv, wbv, pW, pR, la, paA, paB)                                  \
  do {                                                                         \
    unsigned wlo = (unsigned)((wbv) >> lg4);                                   \
    unsigned whi = ((unsigned)((wbv) >> 32)) >> lg4;                           \
    _Pragma("unroll")                                                          \
    for (int kt = 0; kt < 4; ++kt) {                                           \
      unsigned word = (kt < 2) ? wlo : whi;                                    \
      float pv[4];                                                             \
      _Pragma("unroll")                                                        \
      for (int r = 0; r < 4; ++r) {                                            \
        float e = __builtin_amdgcn_exp2f(sv[kt][r]);                           \
        int mb;                                                                \
        asm("v_bfe_i32 %0, %1, %2, 1" : "=v"(mb)                               \
            : "v"(word), "n"((kt & 1) * 16 + r));                              \
        pv[r] = __builtin_bit_cast(float,                                      \
                   __builtin_bit_cast(unsigned, e) & (unsigned)mb);            \
      }                                                                        \
      unsigned pk0, pk1;                                                       \
      asm("v_cvt_pk_bf16_f32 %0, %1, %2" : "=v"(pk0) : "v"(pv[0]), "v"(pv[1]));\
      asm("v_cvt_pk_bf16_f32 %0, %1, %2" : "=v"(pk1) : "v"(pv[2]), "v"(pv[3]));\
      uint2 pr; pr.x = pk0; pr.y = pk1;                                        \
      *(uint2*)(pW + kt * 16) = pr;                                            \
    }                                                                          \
    paA = *(const short8*)(pR);                                                \
    paB = *(const short8*)(pR + 32);                                           \
    la = mfma16(ones, paA, la);                                                \
    la = mfma16(ones, paB, la);                                                \
  } while (0)

#define BODY(buf, i)                                                           \
  do {                                                                         \
    asm volatile("s_waitcnt vmcnt(0)" ::: "memory");                           \
    __builtin_amdgcn_s_barrier();                                              \
    if ((i) + 1 < 16) { ADV(); STAGE(buf ^ 1); }                               \
    unsigned long long nb0 = ((i) + 1 < 16) ? bp0[(i) + 1] : 0ull;             \
    unsigned long long nb1 = ((i) + 1 < 16) ? bp1[(i) + 1] : 0ull;             \
    f32x4 s0[4], s1[4];                                                        \
    _Pragma("unroll")                                                          \
    for (int kt = 0; kt < 4; ++kt) {                                           \
      short8 k0 = *(const short8*)(rdA + (buf) * 4096 + kt * 1024);            \
      short8 k1 = *(const short8*)(rdB + (buf) * 4096 + kt * 1024);            \
      f32x4 z0 = {0.f, 0.f, 0.f, 0.f}, z1 = {0.f, 0.f, 0.f, 0.f};              \
      z0 = mfma16(k0, qf00, z0); s0[kt] = mfma16(k1, qf01, z0);                \
      z1 = mfma16(k0, qf10, z1); s1[kt] = mfma16(k1, qf11, z1);                \
    }                                                                          \
    short8 pa00, pa01, pa10, pa11;                                             \
    SMPACK(s0, wb0, pW0, pR0, la0, pa00, pa01);                                \
    SMPACK(s1, wb1, pW1, pR1, la1, pa10, pa11);                                \
    _Pragma("unroll")                                                          \
    for (int dt = 0; dt < 4; ++dt) {                                           \
      short8 v0 = *(const short8*)(rdA + 8192 + (buf) * 4096 + dt * 1024);     \
      short8 v1 = *(const short8*)(rdB + 8192 + (buf) * 4096 + dt * 1024);     \
      of0[dt] = mfma16(v0, pa00, of0[dt]);                                     \
      of0[dt] = mfma16(v1, pa01, of0[dt]);                                     \
      of1[dt] = mfma16(v0, pa10, of1[dt]);                                     \
      of1[dt] = mfma16(v1, pa11, of1[dt]);                                     \
    }                                                                          \
    wb0 = nb0; wb1 = nb1;                                                      \
  } while (0)

#pragma unroll 1
  for (int it = 0; it < 8; ++it) {
    BODY(0, it * 2);
    BODY(1, it * 2 + 1);
  }
#undef BODY
#undef SMPACK
#undef STAGE
#undef ADV

  // partial outputs (unnormalized, bf16) + partial l (f32)
  u16* Ob = Op + (size_t)sp * N_NODES * DMODEL;
#pragma unroll
  for (int dt = 0; dt < 4; ++dt) {
    ushort4 o0, o1;
#pragma unroll
    for (int r = 0; r < 4; ++r) {
      ((u16*)&o0)[r] = f2bf(of0[dt][r]);
      ((u16*)&o1)[r] = f2bf(of1[dt][r]);
    }
    *(ushort4*)(Ob + (size_t)q0 * DMODEL + h * 64 + dt * 16 + lg4) = o0;
    *(ushort4*)(Ob + (size_t)q1 * DMODEL + h * 64 + dt * 16 + lg4) = o1;
  }
  if (lg == 0) {
    lp[((size_t)sp * NH + h) * N_NODES + q0] = la0[0];
    lp[((size_t)sp * NH + h) * N_NODES + q1] = la1[0];
  }
}

// combine: Oc[q][hd] = bf16( sum_sp Op[sp][q][hd] / sum_sp l[sp][h][q] )
__global__ __launch_bounds__(256) void combine_kernel(const u16* __restrict__ Op,
                                                      const float* __restrict__ lp,
                                                      u16* __restrict__ Oc) {
  int i = blockIdx.x * 256 + threadIdx.x;      // 4 elements per thread
  int col = (i * 4) & (DMODEL - 1);
  int q = (i * 4) >> 9;
  int h = col >> 6;
  float acc0 = 0.f, acc1 = 0.f, acc2 = 0.f, acc3 = 0.f;
  float l = 0.f;
#pragma unroll
  for (int sp = 0; sp < NSPLIT; ++sp) {
    ushort4 a = ((const ushort4*)(Op + (size_t)sp * N_NODES * DMODEL))[i];
    acc0 += bf2f(a.x); acc1 += bf2f(a.y); acc2 += bf2f(a.z); acc3 += bf2f(a.w);
    l += lp[((size_t)sp * NH + h) * N_NODES + q];
  }
  float inv = 1.0f / l;
  ushort4 o;
  o.x = f2bf(acc0 * inv);
  o.y = f2bf(acc1 * inv);
  o.z = f2bf(acc2 * inv);
  o.w = f2bf(acc3 * inv);
  ((ushort4*)Oc)[i] = o;
}

// ---------------- launcher ----------------

extern "C" void kernel_launch(void* const* d_in, const int* in_sizes, int n_in,
                              void* d_out, int out_size, void* d_ws, size_t ws_size,
                              hipStream_t stream) {
  const float* X   = (const float*)d_in[0];
  const float* Adj = (const float*)d_in[1];
  const float* Wks = (const float*)d_in[2];
  const float* Wqs = (const float*)d_in[3];
  const float* Wvs = (const float*)d_in[4];
  const float* Wo  = (const float*)d_in[5];

  char* p = (char*)d_ws;
  u16* Wt  = (u16*)p; p += (size_t)3 * DMODEL * DMODEL * 2;
  u16* Wot = (u16*)p; p += (size_t)DMODEL * DMODEL * 2;
  u16* QKV = (u16*)p; p += (size_t)N_NODES * QKVLD * 2;
  u16* Vt  = (u16*)p; p += (size_t)N_NODES * DMODEL * 2;
  u16* Oc  = (u16*)p; p += (size_t)N_NODES * DMODEL * 2;
  unsigned long long* bits = (unsigned long long*)p; p += (size_t)N_NODES * 64 * 8;
  u16* Op = (u16*)p; p += (size_t)NSPLIT * N_NODES * DMODEL * 2;
  float* lp = (float*)p; p += (size_t)NSPLIT * NH * N_NODES * 4;

  pack_w<<<dim3(8, 1, 32), dim3(256), 0, stream>>>(Wqs, Wks, Wvs, Wo, Wt, Wot);
  build_bits<<<dim3(2048), dim3(256), 0, stream>>>(Adj, bits);

  // fused f32->bf16 convert + Q|K|V projection + V-transpose epilogue
  gemm_qkv<<<dim3(64, 24), dim3(256), 0, stream>>>(X, Wt, QKV, Vt);

  attn_kernel<<<dim3(512), dim3(512), 0, stream>>>(QKV, Vt, bits, Op, lp);
  combine_kernel<<<dim3(N_NODES * DMODEL / 4 / 256), dim3(256), 0, stream>>>(Op, lp, Oc);

  gemm_out<<<dim3(64, 8), dim3(256), 0, stream>>>(Oc, Wot, (float*)d_out);
}